// Round 5
// baseline (64.246 us; speedup 1.0000x reference)
//
#include <hip/hip_runtime.h>

// GrCNetConvOnly: out[b] = sum_{c,d} relu(wa[c]*h[b,d]+wb[c]*r[b,d]+wc[c]*t[b,d]+cb[c]) * fcw[c*D+d] + fcb
// B=16384, D=400, C=50.
// Packed-f16 along c: s-pair for channels (c,c+1) shares broadcast h/r/t -> v_pk_fma_f16
// halves the f32 issue floor (~26us -> ~13us). fc_w staged once per block in LDS as f16
// transposed [d][c]: inner read = one ds_read_b32, immediate offset, conflict-free
// (row stride 100B -> bank stride 25, coprime to 32). No unions, no runtime-indexed
// arrays (R3 spilled: 614MB scratch). 4 b/wave, 4 waves/block, 1024 blocks.

typedef _Float16 half2v __attribute__((ext_vector_type(2)));
typedef _Float16 half8v __attribute__((ext_vector_type(8)));

constexpr int D  = 400;
constexpr int C  = 50;
constexpr int CP = C / 2;   // 25 channel-pairs

__global__ __launch_bounds__(256, 4) void grcnet_pk16(
    const float* __restrict__ entity_emb,
    const float* __restrict__ relation_emb,
    const float* __restrict__ conv_w,       // (C,1,1,3)
    const float* __restrict__ conv_b,       // (C)
    const float* __restrict__ fc_w,         // (C*D), c-major
    const float* __restrict__ fc_b,         // (1)
    const int*   __restrict__ batch_inputs, // (B,3)
    float* __restrict__ out,                // (B)
    int nB)
{
    __shared__ _Float16 fc_lds[D][C];       // 40000 B, [d][c], rows 100 B
    __shared__ half8v   conv_lds[CP];       // 400 B: {wa2, wb2, wc2, cb2} per pair
    __shared__ float    partials[4][4];     // [wave][b]

    const int tid  = threadIdx.x;
    const int lane = tid & 63;
    const int wv   = tid >> 6;
    const int b0   = blockIdx.x * 16;
    if (b0 >= nB) return;

    // ---- stage fc_w (f32 c-major) -> fc_lds (f16 [d][c]) ----
    for (int k = tid; k < D * CP; k += 256) {
        const int cp = k / D;               // 0..24
        const int d  = k - cp * D;          // 0..399
        const int c0 = 2 * cp;
        const _Float16 g0 = (_Float16)fc_w[c0 * D + d];
        const _Float16 g1 = (_Float16)fc_w[c0 * D + D + d];
        half2v g; g[0] = g0; g[1] = g1;
        *(half2v*)&fc_lds[d][c0] = g;
    }
    // ---- stage conv params as duplicated-pair half8 ----
    if (tid < CP) {
        const int c0 = 2 * tid;
        half8v cv;
        cv[0] = (_Float16)conv_w[3*c0+0]; cv[1] = (_Float16)conv_w[3*c0+3];
        cv[2] = (_Float16)conv_w[3*c0+1]; cv[3] = (_Float16)conv_w[3*c0+4];
        cv[4] = (_Float16)conv_w[3*c0+2]; cv[5] = (_Float16)conv_w[3*c0+5];
        cv[6] = (_Float16)conv_b[c0];     cv[7] = (_Float16)conv_b[c0+1];
        conv_lds[tid] = cv;
    }
    __syncthreads();

    // ---- this wave's 4 batch elements ----
    const int bbase = __builtin_amdgcn_readfirstlane(b0 + 4 * wv);
    const int* bi = batch_inputs + 3 * bbase;
    const int h0i = bi[0], r0i = bi[1], t0i = bi[2];
    const int h1i = bi[3], r1i = bi[4], t1i = bi[5];
    const int h2i = bi[6], r2i = bi[7], t2i = bi[8];
    const int h3i = bi[9], r3i = bi[10], t3i = bi[11];

    const float* eh0 = entity_emb   + (size_t)h0i * D;
    const float* er0 = relation_emb + (size_t)r0i * D;
    const float* et0 = entity_emb   + (size_t)t0i * D;
    const float* eh1 = entity_emb   + (size_t)h1i * D;
    const float* er1 = relation_emb + (size_t)r1i * D;
    const float* et1 = entity_emb   + (size_t)t1i * D;
    const float* eh2 = entity_emb   + (size_t)h2i * D;
    const float* er2 = relation_emb + (size_t)r2i * D;
    const float* et2 = entity_emb   + (size_t)t2i * D;
    const float* eh3 = entity_emb   + (size_t)h3i * D;
    const float* er3 = relation_emb + (size_t)r3i * D;
    const float* et3 = entity_emb   + (size_t)t3i * D;

    float acc0 = 0.f, acc1 = 0.f, acc2 = 0.f, acc3 = 0.f;
    const half2v zero2 = (half2v)(_Float16)0;

    for (int i = 0; i < 7; ++i) {
        const int d = lane + 64 * i;
        const bool act = (d < D);
        const int dc = act ? d : 0;

        // gather + convert + duplicate into half2 broadcasts
        const _Float16 h0s = (_Float16)eh0[dc], r0s = (_Float16)er0[dc], t0s = (_Float16)et0[dc];
        const _Float16 h1s = (_Float16)eh1[dc], r1s = (_Float16)er1[dc], t1s = (_Float16)et1[dc];
        const _Float16 h2s = (_Float16)eh2[dc], r2s = (_Float16)er2[dc], t2s = (_Float16)et2[dc];
        const _Float16 h3s = (_Float16)eh3[dc], r3s = (_Float16)er3[dc], t3s = (_Float16)et3[dc];
        half2v h0; h0[0]=h0s; h0[1]=h0s;  half2v r0; r0[0]=r0s; r0[1]=r0s;  half2v t0; t0[0]=t0s; t0[1]=t0s;
        half2v h1; h1[0]=h1s; h1[1]=h1s;  half2v r1; r1[0]=r1s; r1[1]=r1s;  half2v t1; t1[0]=t1s; t1[1]=t1s;
        half2v h2; h2[0]=h2s; h2[1]=h2s;  half2v r2; r2[0]=r2s; r2[1]=r2s;  half2v t2; t2[0]=t2s; t2[1]=t2s;
        half2v h3; h3[0]=h3s; h3[1]=h3s;  half2v r3; r3[0]=r3s; r3[1]=r3s;  half2v t3; t3[0]=t3s; t3[1]=t3s;

        half2v la0 = zero2, la1 = zero2, la2 = zero2, la3 = zero2;

        #pragma unroll
        for (int cp = 0; cp < CP; ++cp) {
            const half8v cv = conv_lds[cp];              // broadcast ds_read_b128
            half2v wa; wa[0]=cv[0]; wa[1]=cv[1];
            half2v wb; wb[0]=cv[2]; wb[1]=cv[3];
            half2v wc; wc[0]=cv[4]; wc[1]=cv[5];
            half2v cb; cb[0]=cv[6]; cb[1]=cv[7];
            const half2v f2 = *(const half2v*)&fc_lds[dc][2*cp];   // ds_read_b32

            half2v s0 = h0*wa + (r0*wb + (t0*wc + cb));
            half2v s1 = h1*wa + (r1*wb + (t1*wc + cb));
            half2v s2 = h2*wa + (r2*wb + (t2*wc + cb));
            half2v s3 = h3*wa + (r3*wb + (t3*wc + cb));
            s0 = __builtin_elementwise_max(s0, zero2);
            s1 = __builtin_elementwise_max(s1, zero2);
            s2 = __builtin_elementwise_max(s2, zero2);
            s3 = __builtin_elementwise_max(s3, zero2);
            la0 = s0 * f2 + la0;
            la1 = s1 * f2 + la1;
            la2 = s2 * f2 + la2;
            la3 = s3 * f2 + la3;
        }

        if (act) {
            acc0 += (float)la0[0] + (float)la0[1];
            acc1 += (float)la1[0] + (float)la1[1];
            acc2 += (float)la2[0] + (float)la2[1];
            acc3 += (float)la3[0] + (float)la3[1];
        }
    }

    // wave-wide sum
    #pragma unroll
    for (int off = 32; off > 0; off >>= 1) {
        acc0 += __shfl_xor(acc0, off);
        acc1 += __shfl_xor(acc1, off);
        acc2 += __shfl_xor(acc2, off);
        acc3 += __shfl_xor(acc3, off);
    }
    if (lane == 0) {
        partials[wv][0] = acc0;
        partials[wv][1] = acc1;
        partials[wv][2] = acc2;
        partials[wv][3] = acc3;
    }
    __syncthreads();

    if (tid < 16) {
        const int w = tid >> 2, j = tid & 3;
        out[b0 + 4*w + j] = partials[w][j] + fc_b[0];
    }
}

extern "C" void kernel_launch(void* const* d_in, const int* in_sizes, int n_in,
                              void* d_out, int out_size, void* d_ws, size_t ws_size,
                              hipStream_t stream) {
    const float* entity_emb   = (const float*)d_in[0];
    const float* relation_emb = (const float*)d_in[1];
    const float* conv_w       = (const float*)d_in[2];
    const float* conv_b       = (const float*)d_in[3];
    const float* fc_w         = (const float*)d_in[4];
    const float* fc_b         = (const float*)d_in[5];
    const int*   batch_inputs = (const int*)d_in[6];
    float* out = (float*)d_out;

    const int nB = in_sizes[6] / 3;          // 16384
    const int blocks = (nB + 15) / 16;       // 1024
    grcnet_pk16<<<blocks, 256, 0, stream>>>(
        entity_emb, relation_emb, conv_w, conv_b, fc_w, fc_b, batch_inputs, out, nB);
}